// Round 2
// baseline (86.153 us; speedup 1.0000x reference)
//
#include <hip/hip_runtime.h>
#include <math.h>

// MinibatchDiscrimination: B=512, IN=512, OUT=100, K=5
//   M = x @ T.view(512,500)                                  [512,500]
//   out[j,o] = sum_i exp(-sum_k |M[i,o,k]-M[j,o,k]|) - 1     [512,100]
//
// Pipeline (3 dispatches, no atomics — R3 showed cross-XCD fp32 atomics
// write-through at ~52MB and serialize; 54us vs <10us expected):
//  k1 gemm   : K-split x8, 64x64 tiles, 4x4 micro, b128 LDS reads
//              -> Mpart[8][512][500]                          (512 blocks)
//  k2 reduce : float4-vectorized sum of 8 partials -> M8[512][800]
//              (padded layout M8[b][o*8+k]), pre-scaled by log2(e) so
//              pairwise can use native v_exp_f32 (exp2) w/o per-pair mul
//  k3 pair   : per (o, 64-j chunk) block, 2 j's PER THREAD — halves the
//              DS-instr count per (i,j) pair (DS pipe was the modeled
//              bottleneck: broadcast b128+b32 per pair -> per 2 pairs)

#define NB    512
#define NIN   512
#define NOUT  100
#define KDIM  5
#define NCOL  (NOUT*KDIM)       // 500
#define KZ    8                 // K-split factor
#define MP_ELEMS (NB*NCOL)      // 256000 per partial
#define M8_LD 800               // padded row stride of M8 (8 floats per o)
#define LOG2E 1.4426950408889634f

// ---------------- Kernel 1: partial GEMM, 64x64 tile, K=64 per block
__global__ __launch_bounds__(256) void gemm_kernel(const float* __restrict__ A,
                                                   const float* __restrict__ Bm,
                                                   float* __restrict__ Mpart) {
    // stride 68 words: float4 rows stay 16B-aligned (68*4 % 16 == 0)
    __shared__ float As[64][68];
    __shared__ float Bs[64][68];

    const int tx = threadIdx.x;            // 0..15 (n)
    const int ty = threadIdx.y;            // 0..15 (m)
    const int tid = ty * 16 + tx;
    const int bn = blockIdx.x * 64;        // n-tile
    const int bm = blockIdx.y * 64;        // m-tile
    const int kz = blockIdx.z;             // 0..7
    const int kt = kz * 64;                // k-chunk

    // stage A tile: 64 rows x 64 k (1024 float4, coalesced)
    #pragma unroll
    for (int l = 0; l < 4; ++l) {
        int idx = tid + l * 256;
        int row = idx >> 4, q = idx & 15;
        float4 v = *reinterpret_cast<const float4*>(&A[(bm + row) * NIN + kt + q * 4]);
        *reinterpret_cast<float4*>(&As[row][q * 4]) = v;
    }
    // stage B tile: 64 k-rows x 64 n (guarded at col>=500)
    #pragma unroll
    for (int l = 0; l < 4; ++l) {
        int idx = tid + l * 256;
        int row = idx >> 4, q = idx & 15;
        int col = bn + q * 4;
        float4 v;
        if (col + 3 < NCOL) {
            v = *reinterpret_cast<const float4*>(&Bm[(kt + row) * NCOL + col]);
        } else {
            v.x = (col + 0 < NCOL) ? Bm[(kt + row) * NCOL + col + 0] : 0.f;
            v.y = (col + 1 < NCOL) ? Bm[(kt + row) * NCOL + col + 1] : 0.f;
            v.z = (col + 2 < NCOL) ? Bm[(kt + row) * NCOL + col + 2] : 0.f;
            v.w = (col + 3 < NCOL) ? Bm[(kt + row) * NCOL + col + 3] : 0.f;
        }
        *reinterpret_cast<float4*>(&Bs[row][q * 4]) = v;
    }
    __syncthreads();

    float acc[4][4];
    #pragma unroll
    for (int i = 0; i < 4; ++i)
        #pragma unroll
        for (int j = 0; j < 4; ++j) acc[i][j] = 0.f;

    // 4-k-unrolled inner loop: all LDS reads are ds_read_b128
    #pragma unroll 4
    for (int k = 0; k < 64; k += 4) {
        float4 a4[4], b4[4];
        #pragma unroll
        for (int i = 0; i < 4; ++i)
            a4[i] = *reinterpret_cast<const float4*>(&As[ty * 4 + i][k]);   // A[m_i][k..k+3]
        #pragma unroll
        for (int kk = 0; kk < 4; ++kk)
            b4[kk] = *reinterpret_cast<const float4*>(&Bs[k + kk][tx * 4]); // B[k+kk][n..n+3]
        #pragma unroll
        for (int kk = 0; kk < 4; ++kk) {
            const float* bp = reinterpret_cast<const float*>(&b4[kk]);
            #pragma unroll
            for (int i = 0; i < 4; ++i) {
                const float a = reinterpret_cast<const float*>(&a4[i])[kk];
                #pragma unroll
                for (int j = 0; j < 4; ++j) acc[i][j] += a * bp[j];
            }
        }
    }

    // epilogue: plain coalesced stores into this kz's partial buffer
    float* C = Mpart + kz * MP_ELEMS;
    #pragma unroll
    for (int i = 0; i < 4; ++i) {
        const int row = bm + ty * 4 + i;
        const int col0 = bn + tx * 4;
        if (col0 + 3 < NCOL) {
            float4 v = make_float4(acc[i][0], acc[i][1], acc[i][2], acc[i][3]);
            *reinterpret_cast<float4*>(&C[row * NCOL + col0]) = v;
        } else {
            #pragma unroll
            for (int j = 0; j < 4; ++j)
                if (col0 + j < NCOL) C[row * NCOL + col0 + j] = acc[i][j];
        }
    }
}

// ---------------- Kernel 2: sum KZ partials -> M8[512][800] (M8[b][o*8+k])
// One float4 per thread: 500 = 4*125, so a float4 never straddles a row.
// Pre-scales by log2(e): pairwise then computes exp2(-norm2) == exp(-norm)
// with a bare v_exp_f32 (no per-pair base-conversion mul).
__global__ __launch_bounds__(256) void reduce_kernel(const float* __restrict__ Mpart,
                                                     float* __restrict__ M8) {
    const unsigned n = blockIdx.x * 256 + threadIdx.x;    // 0..63999 float4 idx
    const float4* P = reinterpret_cast<const float4*>(Mpart);
    float4 s = P[n];
    #pragma unroll
    for (int z = 1; z < KZ; ++z) {
        float4 v = P[z * (MP_ELEMS / 4) + n];
        s.x += v.x; s.y += v.y; s.z += v.z; s.w += v.w;
    }
    const unsigned b  = n / 125;           // row
    const unsigned c  = (n - b * 125) * 4; // col of element 0
    const float sv[4] = {s.x * LOG2E, s.y * LOG2E, s.z * LOG2E, s.w * LOG2E};
    #pragma unroll
    for (int e = 0; e < 4; ++e) {
        const unsigned col = c + e;
        const unsigned o   = col / KDIM;
        const unsigned kk  = col - o * KDIM;
        M8[b * M8_LD + o * 8 + kk] = sv[e];
    }
}

// ---------------- Kernel 3: pairwise L1 + exp2 + reduce over i
// grid (100, 8): block = (o, 64 j's). 256 threads = 32 lanes x 2 j each,
// 8 i-splits (64 i each). Each iteration's 2 broadcast DS reads (b128+b32)
// now feed TWO (i,j) pairs -> total wave-DS-instrs halve vs the 1-j/thread
// version (819K -> 410K); per-iter loop/address overhead amortizes 2x.
__global__ __launch_bounds__(256) void pairwise_kernel(const float* __restrict__ M8,
                                                       float* __restrict__ out) {
    __shared__ float Ms[NB * 8];      // 16 KiB
    __shared__ float red[64][9];      // +1 pad: conflict-free column writes

    const int o   = blockIdx.x;       // 0..99
    const int jc  = blockIdx.y;       // 0..7
    const int tid = threadIdx.x;      // 0..255

    // stage M8[:, o*8 .. o*8+7] -> Ms; lane pairs read the two float4s of a row
    {
        const int half = tid & 1;
        for (int b = tid >> 1; b < NB; b += 128) {
            const float* src = M8 + b * M8_LD + o * 8 + half * 4;
            *reinterpret_cast<float4*>(&Ms[b * 8 + half * 4]) =
                *reinterpret_cast<const float4*>(src);
        }
    }
    __syncthreads();

    const int jl = tid & 31;          // local j lane
    const int ig = tid >> 5;          // i-split group 0..7
    const int jA = jc * 64 + jl;
    const int jB = jA + 32;
    const int i0 = ig * 64;

    const float4 av = *reinterpret_cast<const float4*>(&Ms[jA * 8]);
    const float  a4 = Ms[jA * 8 + 4];
    const float4 bv = *reinterpret_cast<const float4*>(&Ms[jB * 8]);
    const float  b4 = Ms[jB * 8 + 4];

    float accA = 0.0f, accB = 0.0f;
    #pragma unroll 8
    for (int i = i0; i < i0 + 64; ++i) {
        float4 v = *reinterpret_cast<const float4*>(&Ms[i * 8]);
        float v4 = Ms[i * 8 + 4];
        float nA = fabsf(v.x - av.x) + fabsf(v.y - av.y) + fabsf(v.z - av.z)
                 + fabsf(v.w - av.w) + fabsf(v4 - a4);
        float nB = fabsf(v.x - bv.x) + fabsf(v.y - bv.y) + fabsf(v.z - bv.z)
                 + fabsf(v.w - bv.w) + fabsf(v4 - b4);
        accA += exp2f(-nA);            // M8 pre-scaled by log2(e): == exp(-norm)
        accB += exp2f(-nB);            // lowers to bare v_exp_f32
    }

    red[jl][ig]      = accA;
    red[jl + 32][ig] = accB;
    __syncthreads();

    if (tid < 64) {
        float tot = -1.0f;            // remove exp(0) self-term
        #pragma unroll
        for (int g = 0; g < 8; ++g) tot += red[tid][g];
        out[(jc * 64 + tid) * NOUT + o] = tot;
    }
}

extern "C" void kernel_launch(void* const* d_in, const int* in_sizes, int n_in,
                              void* d_out, int out_size, void* d_ws, size_t ws_size,
                              hipStream_t stream) {
    const float* x = (const float*)d_in[0];   // [512,512]
    const float* T = (const float*)d_in[1];   // [512,500]
    float* Mpart = (float*)d_ws;                          // 8 * 1.024 MB
    float* M8    = (float*)d_ws + KZ * MP_ELEMS;          // 512*800*4 = 1.6 MB
    float* out   = (float*)d_out;                         // [512,100]

    gemm_kernel<<<dim3(8, 8, KZ), dim3(16, 16), 0, stream>>>(x, T, Mpart);
    reduce_kernel<<<250, 256, 0, stream>>>(Mpart, M8);
    pairwise_kernel<<<dim3(NOUT, 8), 256, 0, stream>>>(M8, out);
}